// Round 6
// baseline (483.537 us; speedup 1.0000x reference)
//
#include <hip/hip_runtime.h>
#include <hip/hip_bf16.h>

#define IN_F 1024
#define OUT_F 1024
#define QP 9                   // silu + 8 spline bases per input feature
#define KDIM (IN_F * QP)       // 9216
#define BM 256
#define BN 128
#define BK 64
#define SPLITK 4
#define KSLICE (KDIM / SPLITK) // 2304
#define NT (KSLICE / BK)       // 36

typedef __attribute__((ext_vector_type(8)))  short short8;           // MFMA A/B frag (8 bf16)
typedef __attribute__((ext_vector_type(16))) float floatx16;         // 32x32 MFMA C/D frag
typedef __attribute__((ext_vector_type(8)))  unsigned short ushort8v;// 16B bf16 vector

__device__ __forceinline__ unsigned short f2bf(float f) {
    union { float f; unsigned u; } v; v.f = f;
    return (unsigned short)((v.u + 0x7FFF + ((v.u >> 16) & 1)) >> 16); // RNE
}
__device__ __forceinline__ float bf2f(unsigned short h) {
    union { unsigned u; float f; } v; v.u = ((unsigned)h) << 16;
    return v.f;
}

// ============ fused pack: A [B,KDIM] + W [OUT,KDIM], bf16; k = s*IN_F + i ============
// (round-2 version, unchanged)
__global__ __launch_bounds__(256) void pack_kernel(const float* __restrict__ x,
                                                   const float* __restrict__ bw,
                                                   const float* __restrict__ sw,
                                                   __hip_bfloat16* __restrict__ A,
                                                   __hip_bfloat16* __restrict__ W, int Bm) {
    const int nb_a = (Bm * IN_F / 8) / 256;
    if ((int)blockIdx.x < nb_a) {
        int t  = blockIdx.x * 256 + threadIdx.x;   // one thread = 8 features of one row
        int b  = t >> 7;
        int i0 = (t & 127) * 8;
        const float4* xr = (const float4*)(x + (size_t)b * IN_F + i0);
        float4 x0 = xr[0], x1 = xr[1];
        float xv[8] = {x0.x, x0.y, x0.z, x0.w, x1.x, x1.y, x1.z, x1.w};
        ushort8v ov[9];
#pragma unroll
        for (int e = 0; e < 8; ++e) {
            float v  = xv[e];
            float u  = (v + 1.0f) * 5.5f;
            float fj = floorf(u);
            int   j  = (int)fj;
            float tt = u - fj;
            float t2 = tt * tt, t3 = t2 * tt;
            float omt = 1.0f - tt;
            float w0 = omt * omt * omt * (1.0f / 6.0f);                           // q=j-3
            float w1 = (3.0f * t3 - 6.0f * t2 + 4.0f) * (1.0f / 6.0f);            // q=j-2
            float w2 = (-3.0f * t3 + 3.0f * t2 + 3.0f * tt + 1.0f) * (1.0f/6.0f); // q=j-1
            float w3 = t3 * (1.0f / 6.0f);                                        // q=j
            ov[0][e] = f2bf(v * __builtin_amdgcn_rcpf(1.0f + __expf(-v)));        // silu
#pragma unroll
            for (int q = 0; q < 8; ++q) {
                int d = j - q;
                float bv = (d == 3) ? w0 : (d == 2) ? w1 : (d == 1) ? w2 : (d == 0) ? w3 : 0.0f;
                ov[1 + q][e] = f2bf(bv);
            }
        }
        unsigned short* dst = (unsigned short*)A + (size_t)b * KDIM + i0;
#pragma unroll
        for (int s = 0; s < QP; ++s)
            *(ushort8v*)(dst + (size_t)s * IN_F) = ov[s];        // coalesced 16B
    } else {
        int t = ((int)blockIdx.x - nb_a) * 256 + threadIdx.x;    // one (o,i)
        unsigned short* dst = (unsigned short*)W + (size_t)(t >> 10) * KDIM + (t & 1023);
        dst[0] = f2bf(bw[t]);
        const float4* s4 = (const float4*)(sw + (size_t)t * 8);  // 32B contiguous/thread
        float4 lo = s4[0], hi = s4[1];
        dst[1 * IN_F] = f2bf(lo.x); dst[2 * IN_F] = f2bf(lo.y);
        dst[3 * IN_F] = f2bf(lo.z); dst[4 * IN_F] = f2bf(lo.w);
        dst[5 * IN_F] = f2bf(hi.x); dst[6 * IN_F] = f2bf(hi.y);
        dst[7 * IN_F] = f2bf(hi.z); dst[8 * IN_F] = f2bf(hi.w);  // coalesced across lanes
    }
}

// ============ split-K GEMM: 256x128 tile, BK=64, SINGLE 48 KB buffer ============
// Occupancy play (rounds 0-5 post-mortem): round-2's 5770 cyc/tile vs ~2000 cyc
// of LDS data traffic = per-wave read->MFMA serialization at 2 waves/SIMD
// (128 KB LDS -> 1 block/CU). Here: 48 KB LDS -> 3 blocks/CU = 6 waves/SIMD;
// cross-block overlap (m114) hides load-land + barrier stalls. Single buffer
// -> no staging writes in flight during ds_reads -> bank conflicts ~0
// (round-0 evidence: same swizzle class measured 0.0).
// acc[2][2] = 64 AGPR -> ~170 unified regs/wave; 6 waves/SIMD fits 2048 pool.
// Do NOT re-fuse the reduce (round 5: agent-scope fences doubled main loop).
#define GLD(src, dst) __builtin_amdgcn_global_load_lds( \
        (const __attribute__((address_space(1))) void*)(src), \
        (__attribute__((address_space(3))) void*)(dst), 16, 0, 0)

__global__ __launch_bounds__(512, 6) void gemm_splitk(const __hip_bfloat16* __restrict__ A,
                                                      const __hip_bfloat16* __restrict__ W,
                                                      unsigned short* __restrict__ P, int Bm) {
    __shared__ __align__(16) short sA[BM * BK];   // 32 KB
    __shared__ __align__(16) short sB[BN * BK];   // 16 KB  (48 KB -> 3 blocks/CU)
    const int tid  = threadIdx.x;
    const int lane = tid & 63;
    const int wave = tid >> 6;
    const int r32  = lane & 31;
    const int half = lane >> 5;
    const int wm   = wave >> 1;        // 0..3 : wave rows of 64
    const int wn   = wave & 1;         // 0..1 : wave cols of 64

    // XCD-aware decode: grid 512 = 8 XCD x 64. Per XCD: 4 (xt,zt) combos x 16 yt.
    // The 4 sibling xt-blocks sharing an A panel are co-resident on one XCD ->
    // A panel fetched ~once per XCD into L2; W slice per XCD = 2.36 MB (L2-fit).
    const int b   = (int)blockIdx.x;
    const int xcd = b & 7, ii = b >> 3;            // ii in [0,64)
    const int pp  = xcd * 4 + (ii >> 4);           // [0,32)
    const int xt  = pp & 7, zt = pp >> 3;          // 8 n-tiles, 4 k-slices
    const int yt  = ii & 15;
    const int m0 = yt * BM, n0 = xt * BN, kb = zt * KSLICE;

    const short* Ag = (const short*)A + (size_t)m0 * KDIM + kb;
    const short* Wg = (const short*)W + (size_t)n0 * KDIM + kb;

    // staging: A = 2048 16B-chunks, B = 1024; chunk c: row=c>>3, g=c&7,
    // LDS dest linear (c*16B), global source granule pre-swizzled
    // g ^ ((row>>1)&7) = (c&7) ^ ((c>>4)&7)   [round-0 zero-conflict class]
    const short* pA[4]; const short* pB[2]; int ldA[4], ldB[2];
#pragma unroll
    for (int u = 0; u < 4; ++u) {
        int c  = u * 512 + tid;
        int gs = ((c & 7) ^ ((c >> 4) & 7)) * 8;
        pA[u] = Ag + (size_t)(c >> 3) * KDIM + gs;
        ldA[u] = c * 8;
    }
#pragma unroll
    for (int u = 0; u < 2; ++u) {
        int c  = u * 512 + tid;
        int gs = ((c & 7) ^ ((c >> 4) & 7)) * 8;
        pB[u] = Wg + (size_t)(c >> 3) * KDIM + gs;
        ldB[u] = c * 8;
    }

    // fragment ds_read offsets: row-dependent swizzle (row>>1)&7, rows of 64
    // shorts (128 B): off = row*64 + (((kc*2+half) ^ ((row>>1)&7)) * 8)
    int offA[2][4], offB[2][4];
#pragma unroll
    for (int mi = 0; mi < 2; ++mi) {
        int row = wm * 64 + mi * 32 + r32;
        int sw  = (row >> 1) & 7;
#pragma unroll
        for (int kc = 0; kc < 4; ++kc)
            offA[mi][kc] = row * BK + (((kc * 2 + half) ^ sw) * 8);
    }
#pragma unroll
    for (int ni = 0; ni < 2; ++ni) {
        int row = wn * 64 + ni * 32 + r32;
        int sw  = (row >> 1) & 7;
#pragma unroll
        for (int kc = 0; kc < 4; ++kc)
            offB[ni][kc] = row * BK + (((kc * 2 + half) ^ sw) * 8);
    }

    floatx16 acc[2][2] = {};

    for (int t = 0; t < NT; ++t) {
        const int koff = t * BK;
#pragma unroll
        for (int u = 0; u < 4; ++u) GLD(pA[u] + koff, &sA[ldA[u]]);
#pragma unroll
        for (int u = 0; u < 2; ++u) GLD(pB[u] + koff, &sB[ldB[u]]);
        asm volatile("s_waitcnt vmcnt(0)" ::: "memory");
        __builtin_amdgcn_s_barrier();

        __builtin_amdgcn_s_setprio(1);
#pragma unroll
        for (int kc = 0; kc < 4; ++kc) {
            short8 aF[2], bF[2];
#pragma unroll
            for (int mi = 0; mi < 2; ++mi) aF[mi] = *(const short8*)(sA + offA[mi][kc]);
#pragma unroll
            for (int ni = 0; ni < 2; ++ni) bF[ni] = *(const short8*)(sB + offB[ni][kc]);
#pragma unroll
            for (int mi = 0; mi < 2; ++mi)
#pragma unroll
                for (int ni = 0; ni < 2; ++ni)
                    acc[mi][ni] = __builtin_amdgcn_mfma_f32_32x32x16_bf16(
                        aF[mi], bF[ni], acc[mi][ni], 0, 0, 0);
        }
        __builtin_amdgcn_s_setprio(0);
        __builtin_amdgcn_s_barrier();   // reads consumed before next overwrite
    }

    // C/D layout (m74/m101-verified): col = lane&31, row = (reg&3) + 8*(reg>>2) + 4*(lane>>5)
    unsigned short* Pz = P + (size_t)zt * Bm * OUT_F;
#pragma unroll
    for (int mi = 0; mi < 2; ++mi)
#pragma unroll
        for (int ni = 0; ni < 2; ++ni)
#pragma unroll
            for (int r = 0; r < 16; ++r) {
                int row = (r & 3) + 8 * (r >> 2) + 4 * half;
                int gm  = m0 + wm * 64 + mi * 32 + row;
                Pz[(size_t)gm * OUT_F + n0 + wn * 64 + ni * 32 + r32] = f2bf(acc[mi][ni][r]);
            }
}

// ============ reduce: C = sum_j P_j (bf16 partials -> fp32 out), 8 elems/thread ====
__global__ __launch_bounds__(256) void reduce_kernel(const unsigned short* __restrict__ P,
                                                     float* __restrict__ C, int n) {
    int t  = blockIdx.x * 256 + threadIdx.x;
    int i0 = t * 8;
    float o[8] = {0.f, 0.f, 0.f, 0.f, 0.f, 0.f, 0.f, 0.f};
#pragma unroll
    for (int j = 0; j < SPLITK; ++j) {
        ushort8v a = *(const ushort8v*)(P + (size_t)j * n + i0);
#pragma unroll
        for (int e = 0; e < 8; ++e) o[e] += bf2f(a[e]);
    }
    float4 o0, o1;
    o0.x = o[0]; o0.y = o[1]; o0.z = o[2]; o0.w = o[3];
    o1.x = o[4]; o1.y = o[5]; o1.z = o[6]; o1.w = o[7];
    *(float4*)(C + i0)     = o0;
    *(float4*)(C + i0 + 4) = o1;
}

// ---- fp32 fallback (tiny ws / unexpected shape) ----
__global__ __launch_bounds__(256) void fallback_kernel(const float* __restrict__ x,
                                                       const float* __restrict__ bw,
                                                       const float* __restrict__ sw,
                                                       const float* __restrict__ grid,
                                                       float* __restrict__ out, int Bm) {
    __shared__ float sv[256][QP + 1];
    int b = blockIdx.y;
    int o = blockIdx.x * 256 + threadIdx.x;
    float acc = 0.f;
    for (int ic = 0; ic < IN_F; ic += 256) {
        int i = ic + threadIdx.x;
        float v = x[(size_t)b * IN_F + i];
        float g[12];
        for (int j = 0; j < 12; ++j) g[j] = grid[j];
        float bb[11];
        for (int j = 0; j < 11; ++j) bb[j] = (v >= g[j] && v < g[j + 1]) ? 1.f : 0.f;
        for (int k = 1; k <= 3; ++k)
            for (int j = 0; j < 11 - k; ++j)
                bb[j] = (v - g[j]) / (g[j + k] - g[j] + 1e-8f) * bb[j]
                      + (g[j + k + 1] - v) / (g[j + k + 1] - g[j + 1] + 1e-8f) * bb[j + 1];
        __syncthreads();
        sv[threadIdx.x][0] = v / (1.f + __expf(-v));
        for (int q = 0; q < 8; ++q) sv[threadIdx.x][1 + q] = bb[q];
        __syncthreads();
        for (int ii = 0; ii < 256; ++ii) {
            int i2 = ic + ii;
            acc += sv[ii][0] * bw[(size_t)o * IN_F + i2];
            const float* swp = sw + ((size_t)o * IN_F + i2) * 8;
            for (int q = 0; q < 8; ++q) acc += sv[ii][1 + q] * swp[q];
        }
    }
    out[(size_t)b * OUT_F + o] = acc;
}

extern "C" void kernel_launch(void* const* d_in, const int* in_sizes, int n_in,
                              void* d_out, int out_size, void* d_ws, size_t ws_size,
                              hipStream_t stream) {
    const float* x    = (const float*)d_in[0];
    const float* bw   = (const float*)d_in[1];
    const float* sw   = (const float*)d_in[2];
    const float* grid = (const float*)d_in[3];
    float* out = (float*)d_out;

    const int Bm = in_sizes[0] / IN_F;                     // 4096
    const size_t a_bytes = (size_t)Bm * KDIM * sizeof(__hip_bfloat16);
    const size_t w_bytes = (size_t)OUT_F * KDIM * sizeof(__hip_bfloat16);
    const size_t p_bytes = (size_t)SPLITK * Bm * OUT_F * sizeof(unsigned short);

    if (ws_size >= a_bytes + w_bytes + p_bytes && Bm == 4096) {
        __hip_bfloat16* Apk = (__hip_bfloat16*)d_ws;
        __hip_bfloat16* Wpk = (__hip_bfloat16*)((char*)d_ws + a_bytes);
        unsigned short* P = (unsigned short*)((char*)d_ws + a_bytes + w_bytes);
        const int nb_a = (Bm * IN_F / 8) / 256;            // 2048
        const int nb_w = (OUT_F * IN_F) / 256;             // 4096
        pack_kernel<<<nb_a + nb_w, 256, 0, stream>>>(x, bw, sw, Apk, Wpk, Bm);
        gemm_splitk<<<(Bm / BM) * (OUT_F / BN) * SPLITK, 512, 0, stream>>>(Apk, Wpk, P, Bm);
        reduce_kernel<<<Bm * OUT_F / 2048, 256, 0, stream>>>(P, out, Bm * OUT_F);
    } else {
        fallback_kernel<<<dim3(OUT_F / 256, Bm), 256, 0, stream>>>(x, bw, sw, grid, out, Bm);
    }
}

// Round 7
// 196.706 us; speedup vs baseline: 2.4582x; 2.4582x over previous
//
#include <hip/hip_runtime.h>
#include <hip/hip_bf16.h>

#define IN_F 1024
#define OUT_F 1024
#define QP 9                   // silu + 8 spline bases per input feature
#define KDIM (IN_F * QP)       // 9216
#define BM 256
#define BN 256
#define BK 64
#define TILE_SH (BM * BK)      // 16384 shorts = 32 KB per matrix per buffer

typedef __attribute__((ext_vector_type(8)))  short short8;           // MFMA A/B frag (8 bf16)
typedef __attribute__((ext_vector_type(16))) float floatx16;         // 32x32 MFMA C/D frag
typedef __attribute__((ext_vector_type(8)))  unsigned short ushort8v;// 16B bf16 vector

__device__ __forceinline__ unsigned short f2bf(float f) {
    union { float f; unsigned u; } v; v.f = f;
    return (unsigned short)((v.u + 0x7FFF + ((v.u >> 16) & 1)) >> 16); // RNE
}
__device__ __forceinline__ float bf2f(unsigned short h) {
    union { unsigned u; float f; } v; v.u = ((unsigned)h) << 16;
    return v.f;
}

// ============ fused pack: A [B,KDIM] + W [OUT,KDIM], bf16; k = s*IN_F + i ============
// (round-2 version, unchanged)
__global__ __launch_bounds__(256) void pack_kernel(const float* __restrict__ x,
                                                   const float* __restrict__ bw,
                                                   const float* __restrict__ sw,
                                                   __hip_bfloat16* __restrict__ A,
                                                   __hip_bfloat16* __restrict__ W, int Bm) {
    const int nb_a = (Bm * IN_F / 8) / 256;
    if ((int)blockIdx.x < nb_a) {
        int t  = blockIdx.x * 256 + threadIdx.x;   // one thread = 8 features of one row
        int b  = t >> 7;
        int i0 = (t & 127) * 8;
        const float4* xr = (const float4*)(x + (size_t)b * IN_F + i0);
        float4 x0 = xr[0], x1 = xr[1];
        float xv[8] = {x0.x, x0.y, x0.z, x0.w, x1.x, x1.y, x1.z, x1.w};
        ushort8v ov[9];
#pragma unroll
        for (int e = 0; e < 8; ++e) {
            float v  = xv[e];
            float u  = (v + 1.0f) * 5.5f;
            float fj = floorf(u);
            int   j  = (int)fj;
            float tt = u - fj;
            float t2 = tt * tt, t3 = t2 * tt;
            float omt = 1.0f - tt;
            float w0 = omt * omt * omt * (1.0f / 6.0f);                           // q=j-3
            float w1 = (3.0f * t3 - 6.0f * t2 + 4.0f) * (1.0f / 6.0f);            // q=j-2
            float w2 = (-3.0f * t3 + 3.0f * t2 + 3.0f * tt + 1.0f) * (1.0f/6.0f); // q=j-1
            float w3 = t3 * (1.0f / 6.0f);                                        // q=j
            ov[0][e] = f2bf(v * __builtin_amdgcn_rcpf(1.0f + __expf(-v)));        // silu
#pragma unroll
            for (int q = 0; q < 8; ++q) {
                int d = j - q;
                float bv = (d == 3) ? w0 : (d == 2) ? w1 : (d == 1) ? w2 : (d == 0) ? w3 : 0.0f;
                ov[1 + q][e] = f2bf(bv);
            }
        }
        unsigned short* dst = (unsigned short*)A + (size_t)b * KDIM + i0;
#pragma unroll
        for (int s = 0; s < QP; ++s)
            *(ushort8v*)(dst + (size_t)s * IN_F) = ov[s];        // coalesced 16B
    } else {
        int t = ((int)blockIdx.x - nb_a) * 256 + threadIdx.x;    // one (o,i)
        unsigned short* dst = (unsigned short*)W + (size_t)(t >> 10) * KDIM + (t & 1023);
        dst[0] = f2bf(bw[t]);
        const float4* s4 = (const float4*)(sw + (size_t)t * 8);  // 32B contiguous/thread
        float4 lo = s4[0], hi = s4[1];
        dst[1 * IN_F] = f2bf(lo.x); dst[2 * IN_F] = f2bf(lo.y);
        dst[3 * IN_F] = f2bf(lo.z); dst[4 * IN_F] = f2bf(lo.w);
        dst[5 * IN_F] = f2bf(hi.x); dst[6 * IN_F] = f2bf(hi.y);
        dst[7 * IN_F] = f2bf(hi.z); dst[8 * IN_F] = f2bf(hi.w);  // coalesced across lanes
    }
}

// ============ split-K GEMM: 256x256 tile, BK=64, double-buffer (round-2 skeleton) ====
// Round-2 core restored verbatim (best measured: 86.6 us gemm / 197.5 us wall;
// VGPR=100, WRITE 34 MB, FETCH 85 MB). Single change vs round 2: the inner
// loop is an EXPLICIT 2-deep kc pipeline (read kc+1 frags before MFMA kc,
// two named fragment sets, compile-time indices only). Pure instruction-order
// change: same layout, same sync, same traffic.
// Post-mortem constraints (rounds 3-6): do NOT split staging below 128B/row
// granularity (half-line fetch -> L2 victim storm); do NOT drop the double
// buffer (exposed miss latency); do NOT fuse the reduce (agent-scope fences
// double the main loop); occupancy plays at this tile are cache-thrash-bound.
#define GLD(src, dst) __builtin_amdgcn_global_load_lds( \
        (const __attribute__((address_space(1))) void*)(src), \
        (__attribute__((address_space(3))) void*)(dst), 16, 0, 0)

__global__ __launch_bounds__(512, 2) void gemm_splitk(const __hip_bfloat16* __restrict__ A,
                                                      const __hip_bfloat16* __restrict__ W,
                                                      unsigned short* __restrict__ P,
                                                      int Bm, int splitk, int kslice) {
    __shared__ __align__(16) short sA[2][TILE_SH];   // 2 x 32 KB
    __shared__ __align__(16) short sB[2][TILE_SH];   // 2 x 32 KB  (128 KB total)
    const int tid  = threadIdx.x;
    const int lane = tid & 63;
    const int wave = tid >> 6;
    const int r32  = lane & 31;
    const int half = lane >> 5;
    const int wm   = wave >> 2;        // 0..1 : wave rows of 128
    const int wn   = wave & 3;         // 0..3 : wave cols of 64

    // XCD-aware decode (FETCH 304->85 MB, keep)
    const int b   = (int)blockIdx.x;
    const int xcd = b & 7, ii = b >> 3;
    const int pp  = xcd * (splitk >> 1) + (ii >> 4);
    const int xt  = pp & 3, zt = pp >> 2, yt = ii & 15;
    const int m0 = yt * BM, n0 = xt * BN, kb = zt * kslice;
    const int NT = kslice / BK;        // 36 (splitk=4)

    const short* Ag = (const short*)A + (size_t)m0 * KDIM + kb;
    const short* Wg = (const short*)W + (size_t)n0 * KDIM + kb;

    // staging: 2048 16B-chunks per matrix per tile; chunk c = u*512+tid:
    // row = c>>3, gpos = c&7, LDS dest linear (c*16 B), global source granule
    // pre-swizzled gpos ^ (row&7). 128B contiguous per row -> full-line fetch.
    const short* pA[4]; const short* pB[4]; int ldst[4];
#pragma unroll
    for (int u = 0; u < 4; ++u) {
        int c  = u * 512 + tid;
        int gs = ((c & 7) ^ ((c >> 3) & 7)) * 8;
        pA[u] = Ag + (size_t)(c >> 3) * KDIM + gs;
        pB[u] = Wg + (size_t)(c >> 3) * KDIM + gs;
        ldst[u] = c * 8;
    }

    // fragment ds_read offsets: row&7 == r32&7; granule g = kc*2+half,
    // swizzled: off = row*64 + ((g ^ (r32&7))*8)
    const int sw7 = r32 & 7;
    int offA[4][4], offB[2][4];
#pragma unroll
    for (int mi = 0; mi < 4; ++mi) {
        int row = wm * 128 + mi * 32 + r32;
#pragma unroll
        for (int kc = 0; kc < 4; ++kc)
            offA[mi][kc] = row * BK + (((kc * 2 + half) ^ sw7) * 8);
    }
#pragma unroll
    for (int ni = 0; ni < 2; ++ni) {
        int row = wn * 64 + ni * 32 + r32;
#pragma unroll
        for (int kc = 0; kc < 4; ++kc)
            offB[ni][kc] = row * BK + (((kc * 2 + half) ^ sw7) * 8);
    }

    floatx16 acc[4][2] = {};

#define STAGE(bi, koff) do { \
        _Pragma("unroll") \
        for (int u = 0; u < 4; ++u) { \
            GLD(pA[u] + (koff), &sA[bi][ldst[u]]); \
            GLD(pB[u] + (koff), &sB[bi][ldst[u]]); \
        } \
    } while (0)

    // read one kc's fragments into a named set (all indices compile-time)
#define RD(aF, bF, kc) do { \
        aF[0] = *(const short8*)(sAb + offA[0][kc]); \
        aF[1] = *(const short8*)(sAb + offA[1][kc]); \
        aF[2] = *(const short8*)(sAb + offA[2][kc]); \
        aF[3] = *(const short8*)(sAb + offA[3][kc]); \
        bF[0] = *(const short8*)(sBb + offB[0][kc]); \
        bF[1] = *(const short8*)(sBb + offB[1][kc]); \
    } while (0)
#define MM(aF, bF) do { \
        _Pragma("unroll") \
        for (int mi = 0; mi < 4; ++mi) \
            _Pragma("unroll") \
            for (int ni = 0; ni < 2; ++ni) \
                acc[mi][ni] = __builtin_amdgcn_mfma_f32_32x32x16_bf16( \
                    aF[mi], bF[ni], acc[mi][ni], 0, 0, 0); \
    } while (0)

    STAGE(0, 0);                                   // tile 0 in flight (8 loads)

    for (int t = 0; t < NT; ++t) {
        // tile t's loads were issued one full tile ago -> near-zero stall
        asm volatile("s_waitcnt vmcnt(0)" ::: "memory");
        __builtin_amdgcn_s_barrier();

        const int nb = (t + 1 == NT) ? 0 : t + 1;  // wrapped (harmless) prefetch
        STAGE((t + 1) & 1, nb * BK);

        const short* sAb = &sA[t & 1][0];
        const short* sBb = &sB[t & 1][0];

        short8 aP[4], bP[2], aQ[4], bQ[2];
        __builtin_amdgcn_s_setprio(1);
        RD(aP, bP, 0);                 // 2-deep kc pipeline: read k+1 ahead of MFMA k
        RD(aQ, bQ, 1);
        MM(aP, bP);
        RD(aP, bP, 2);
        MM(aQ, bQ);
        RD(aQ, bQ, 3);
        MM(aP, bP);
        MM(aQ, bQ);
        __builtin_amdgcn_s_setprio(0);
    }
#undef STAGE
#undef RD
#undef MM
    asm volatile("s_waitcnt vmcnt(0)" ::: "memory");   // drain wrapped prefetch

    // C/D layout (m74/m101-verified): col = lane&31, row = (reg&3) + 8*(reg>>2) + 4*(lane>>5)
    unsigned short* Pz = P + (size_t)zt * Bm * OUT_F;
#pragma unroll
    for (int mi = 0; mi < 4; ++mi)
#pragma unroll
        for (int ni = 0; ni < 2; ++ni)
#pragma unroll
            for (int r = 0; r < 16; ++r) {
                int row = (r & 3) + 8 * (r >> 2) + 4 * half;
                int gm  = m0 + wm * 128 + mi * 32 + row;
                Pz[(size_t)gm * OUT_F + n0 + wn * 64 + ni * 32 + r32] = f2bf(acc[mi][ni][r]);
            }
}

// ============ reduce: C = sum_j P_j (bf16 partials -> fp32 out), 8 elems/thread ====
__global__ __launch_bounds__(256) void reduce_kernel(const unsigned short* __restrict__ P,
                                                     float* __restrict__ C, int n, int s) {
    int t  = blockIdx.x * 256 + threadIdx.x;
    int i0 = t * 8;
    float o[8] = {0.f, 0.f, 0.f, 0.f, 0.f, 0.f, 0.f, 0.f};
    for (int j = 0; j < s; ++j) {
        ushort8v a = *(const ushort8v*)(P + (size_t)j * n + i0);
#pragma unroll
        for (int e = 0; e < 8; ++e) o[e] += bf2f(a[e]);
    }
    float4 o0, o1;
    o0.x = o[0]; o0.y = o[1]; o0.z = o[2]; o0.w = o[3];
    o1.x = o[4]; o1.y = o[5]; o1.z = o[6]; o1.w = o[7];
    *(float4*)(C + i0)     = o0;
    *(float4*)(C + i0 + 4) = o1;
}

// ---- fp32 fallback (tiny ws / unexpected shape) ----
__global__ __launch_bounds__(256) void fallback_kernel(const float* __restrict__ x,
                                                       const float* __restrict__ bw,
                                                       const float* __restrict__ sw,
                                                       const float* __restrict__ grid,
                                                       float* __restrict__ out, int Bm) {
    __shared__ float sv[256][QP + 1];
    int b = blockIdx.y;
    int o = blockIdx.x * 256 + threadIdx.x;
    float acc = 0.f;
    for (int ic = 0; ic < IN_F; ic += 256) {
        int i = ic + threadIdx.x;
        float v = x[(size_t)b * IN_F + i];
        float g[12];
        for (int j = 0; j < 12; ++j) g[j] = grid[j];
        float bb[11];
        for (int j = 0; j < 11; ++j) bb[j] = (v >= g[j] && v < g[j + 1]) ? 1.f : 0.f;
        for (int k = 1; k <= 3; ++k)
            for (int j = 0; j < 11 - k; ++j)
                bb[j] = (v - g[j]) / (g[j + k] - g[j] + 1e-8f) * bb[j]
                      + (g[j + k + 1] - v) / (g[j + k + 1] - g[j + 1] + 1e-8f) * bb[j + 1];
        __syncthreads();
        sv[threadIdx.x][0] = v / (1.f + __expf(-v));
        for (int q = 0; q < 8; ++q) sv[threadIdx.x][1 + q] = bb[q];
        __syncthreads();
        for (int ii = 0; ii < 256; ++ii) {
            int i2 = ic + ii;
            acc += sv[ii][0] * bw[(size_t)o * IN_F + i2];
            const float* swp = sw + ((size_t)o * IN_F + i2) * 8;
            for (int q = 0; q < 8; ++q) acc += sv[ii][1 + q] * swp[q];
        }
    }
    out[(size_t)b * OUT_F + o] = acc;
}

extern "C" void kernel_launch(void* const* d_in, const int* in_sizes, int n_in,
                              void* d_out, int out_size, void* d_ws, size_t ws_size,
                              hipStream_t stream) {
    const float* x    = (const float*)d_in[0];
    const float* bw   = (const float*)d_in[1];
    const float* sw   = (const float*)d_in[2];
    const float* grid = (const float*)d_in[3];
    float* out = (float*)d_out;

    const int Bm = in_sizes[0] / IN_F;                     // 4096
    const size_t a_bytes = (size_t)Bm * KDIM * sizeof(__hip_bfloat16);
    const size_t w_bytes = (size_t)OUT_F * KDIM * sizeof(__hip_bfloat16);

    int splitk = 4;                                        // 256 blocks = 1/CU
    size_t p_bytes = (size_t)splitk * Bm * OUT_F * sizeof(unsigned short);
    if (ws_size < a_bytes + w_bytes + p_bytes) {
        splitk = 2;                                        // ws-constrained fallback
        p_bytes = (size_t)splitk * Bm * OUT_F * sizeof(unsigned short);
    }

    if (ws_size >= a_bytes + w_bytes + p_bytes && Bm == 4096) {
        __hip_bfloat16* Apk = (__hip_bfloat16*)d_ws;
        __hip_bfloat16* Wpk = (__hip_bfloat16*)((char*)d_ws + a_bytes);
        unsigned short* P = (unsigned short*)((char*)d_ws + a_bytes + w_bytes);
        const int nb_a = (Bm * IN_F / 8) / 256;            // 2048
        const int nb_w = (OUT_F * IN_F) / 256;             // 4096
        pack_kernel<<<nb_a + nb_w, 256, 0, stream>>>(x, bw, sw, Apk, Wpk, Bm);
        gemm_splitk<<<(Bm / BM) * (OUT_F / BN) * splitk, 512, 0, stream>>>(
            Apk, Wpk, P, Bm, splitk, KDIM / splitk);
        reduce_kernel<<<Bm * OUT_F / 2048, 256, 0, stream>>>(P, out, Bm * OUT_F, splitk);
    } else {
        fallback_kernel<<<dim3(OUT_F / 256, Bm), 256, 0, stream>>>(x, bw, sw, grid, out, Bm);
    }
}